// Round 7
// baseline (50183.362 us; speedup 1.0000x reference)
//
#include <hip/hip_runtime.h>
#include <stdint.h>

#define HIST 1792
#define TGT 256
#define SEQ 2048
#define INPUT 352
#define EHID 250
#define HID 500

typedef _Float16 h2_t __attribute__((ext_vector_type(2)));

static __device__ __forceinline__ float fdot2(uint32_t a, uint32_t b, float c) {
  return __builtin_amdgcn_fdot2(__builtin_bit_cast(h2_t, a),
                                __builtin_bit_cast(h2_t, b), c, false);
}
static __device__ __forceinline__ uint32_t packh2(float lo, float hi) {
  h2_t h; h[0] = (_Float16)lo; h[1] = (_Float16)hi;
  return __builtin_bit_cast(uint32_t, h);
}
static __device__ __forceinline__ uint4 packq(const float* p) {
  uint4 r;
  r.x = packh2(p[0], p[1]); r.y = packh2(p[2], p[3]);
  r.z = packh2(p[4], p[5]); r.w = packh2(p[6], p[7]);
  return r;
}
static __device__ __forceinline__ float dotq(uint4 w, uint4 h, float acc) {
  acc = fdot2(w.x, h.x, acc); acc = fdot2(w.y, h.y, acc);
  acc = fdot2(w.z, h.z, acc); acc = fdot2(w.w, h.w, acc);
  return acc;
}
static __device__ __forceinline__ float sigf(float x) {
  x = fminf(fmaxf(x, -30.f), 30.f);
  return 1.f / (1.f + __expf(-x));
}
static __device__ __forceinline__ float tanh_f(float x) {
  x = fminf(fmaxf(x, -15.f), 15.f);
  float e = __expf(2.f * x);
  return (e - 1.f) / (e + 1.f);
}
static __device__ __forceinline__ void spin_flag(volatile int* f) {
  while (__hip_atomic_load(f, __ATOMIC_ACQUIRE, __HIP_MEMORY_SCOPE_AGENT) == 0)
    __builtin_amdgcn_s_sleep(2);
}
// AGPR store/load (gfx950 unified file)
#define AW(dst, src) asm volatile("v_accvgpr_write_b32 %0, %1" : "=a"(dst) : "v"(src))
#define AR(dst, src) asm volatile("v_accvgpr_read_b32 %0, %1" : "=v"(dst) : "a"(src))
#define ARQ(dst, arr, base) do { AR(dst.x, arr[(base)+0]); AR(dst.y, arr[(base)+1]); AR(dst.z, arr[(base)+2]); AR(dst.w, arr[(base)+3]); } while(0)

// ---------------- embedding gather + target_emb ----------------
__global__ void k_embed(const int* __restrict__ loc, const int* __restrict__ tim,
                        const int* __restrict__ cid, const int* __restrict__ target,
                        const float* __restrict__ weight, const float* __restrict__ emb_tim_w,
                        const float* __restrict__ weight_cid,
                        float* __restrict__ x, float* __restrict__ te) {
  int t = blockIdx.x, tid = threadIdx.x;
  if (t < SEQ) {
    int l = loc[t], tm = tim[t], cd = cid[t];
    float* xr = x + (size_t)t * INPUT;
    for (int k = tid; k < 256; k += blockDim.x) xr[k] = weight[(size_t)l * 256 + k];
    for (int k = tid; k < 32; k += blockDim.x)  xr[256 + k] = emb_tim_w[tm * 32 + k];
    for (int k = tid; k < 64; k += blockDim.x)  xr[288 + k] = weight_cid[cd * 64 + k];
  } else {
    int i = t - SEQ;
    int tg = target[i];
    for (int k = tid; k < 256; k += blockDim.x) te[(size_t)i * 256 + k] = weight[(size_t)tg * 256 + k];
  }
}

// ---------------- C[M][N] = op(A)[M][K] @ W[N][K]^T + bias ----------------
__global__ void k_gemm_t(const float* __restrict__ A, int lda,
                         const float* __restrict__ W, const float* __restrict__ bias,
                         float* __restrict__ C, int ldc,
                         int M, int N, int K, int revA) {
  __shared__ float As[16][65];
  __shared__ float Ws[16][65];
  const int bn = blockIdx.x * 64, bm = blockIdx.y * 64;
  const int tid = threadIdx.x;
  const int tx = tid & 15, ty = tid >> 4;
  float acc[4][4] = {};
  for (int k0 = 0; k0 < K; k0 += 16) {
    for (int i = tid; i < 1024; i += 256) {
      int m = i >> 4, k = i & 15;
      int gm = bm + m, gk = k0 + k;
      float v = 0.f;
      if (gm < M && gk < K) { int am = revA ? (M - 1 - gm) : gm; v = A[(size_t)am * lda + gk]; }
      As[k][m] = v;
    }
    for (int i = tid; i < 1024; i += 256) {
      int n = i >> 4, k = i & 15;
      int gn = bn + n, gk = k0 + k;
      float v = 0.f;
      if (gn < N && gk < K) v = W[(size_t)gn * K + gk];
      Ws[k][n] = v;
    }
    __syncthreads();
#pragma unroll
    for (int k = 0; k < 16; k++) {
      float a0 = As[k][ty * 4 + 0], a1 = As[k][ty * 4 + 1], a2 = As[k][ty * 4 + 2], a3 = As[k][ty * 4 + 3];
      float b0 = Ws[k][tx * 4 + 0], b1 = Ws[k][tx * 4 + 1], b2 = Ws[k][tx * 4 + 2], b3 = Ws[k][tx * 4 + 3];
      acc[0][0] += a0 * b0; acc[0][1] += a0 * b1; acc[0][2] += a0 * b2; acc[0][3] += a0 * b3;
      acc[1][0] += a1 * b0; acc[1][1] += a1 * b1; acc[1][2] += a1 * b2; acc[1][3] += a1 * b3;
      acc[2][0] += a2 * b0; acc[2][1] += a2 * b1; acc[2][2] += a2 * b2; acc[2][3] += a2 * b3;
      acc[3][0] += a3 * b0; acc[3][1] += a3 * b1; acc[3][2] += a3 * b2; acc[3][3] += a3 * b3;
    }
    __syncthreads();
  }
  for (int i = 0; i < 4; i++) {
    int gm = bm + ty * 4 + i; if (gm >= M) continue;
    for (int j = 0; j < 4; j++) {
      int gn = bn + tx * 4 + j; if (gn >= N) continue;
      C[(size_t)gm * ldc + gn] = acc[i][j] + (bias ? bias[gn] : 0.f);
    }
  }
}

// ---------------- C[M][N] = A[M][K] @ B[K][N] + addvec[N] ----------------
__global__ void k_gemm_nn(const float* __restrict__ A, int lda,
                          const float* __restrict__ B, int ldb,
                          const float* __restrict__ addvec,
                          float* __restrict__ C, int ldc,
                          int M, int N, int K) {
  __shared__ float As[16][65];
  __shared__ float Bs[16][65];
  const int bn = blockIdx.x * 64, bm = blockIdx.y * 64;
  const int tid = threadIdx.x;
  const int tx = tid & 15, ty = tid >> 4;
  float acc[4][4] = {};
  for (int k0 = 0; k0 < K; k0 += 16) {
    for (int i = tid; i < 1024; i += 256) {
      int m = i >> 4, k = i & 15;
      int gm = bm + m, gk = k0 + k;
      float v = 0.f;
      if (gm < M && gk < K) v = A[(size_t)gm * lda + gk];
      As[k][m] = v;
    }
    for (int i = tid; i < 1024; i += 256) {
      int k = i >> 6, n = i & 63;
      int gk = k0 + k, gn = bn + n;
      float v = 0.f;
      if (gk < K && gn < N) v = B[(size_t)gk * ldb + gn];
      Bs[k][n] = v;
    }
    __syncthreads();
#pragma unroll
    for (int k = 0; k < 16; k++) {
      float a0 = As[k][ty * 4 + 0], a1 = As[k][ty * 4 + 1], a2 = As[k][ty * 4 + 2], a3 = As[k][ty * 4 + 3];
      float b0 = Bs[k][tx * 4 + 0], b1 = Bs[k][tx * 4 + 1], b2 = Bs[k][tx * 4 + 2], b3 = Bs[k][tx * 4 + 3];
      acc[0][0] += a0 * b0; acc[0][1] += a0 * b1; acc[0][2] += a0 * b2; acc[0][3] += a0 * b3;
      acc[1][0] += a1 * b0; acc[1][1] += a1 * b1; acc[1][2] += a1 * b2; acc[1][3] += a1 * b3;
      acc[2][0] += a2 * b0; acc[2][1] += a2 * b1; acc[2][2] += a2 * b2; acc[2][3] += a2 * b3;
      acc[3][0] += a3 * b0; acc[3][1] += a3 * b1; acc[3][2] += a3 * b2; acc[3][3] += a3 * b3;
    }
    __syncthreads();
  }
  for (int i = 0; i < 4; i++) {
    int gm = bm + ty * 4 + i; if (gm >= M) continue;
    for (int j = 0; j < 4; j++) {
      int gn = bn + tx * 4 + j; if (gn >= N) continue;
      C[(size_t)gm * ldc + gn] = acc[i][j] + (addvec ? addvec[gn] : 0.f);
    }
  }
}

// ---------------- LSTMs ----------------
// 6 blocks x 256 threads (250 active), 1 wave/SIMD, 512 regs/thread budget.
//  b0,b1: encoders, GATE-ALIGNED: thread tid owns row tid of gates i,f,g,o.
//    z-gates are thread-private -> no zbuf, 1 barrier/step (h double-buffered).
//    Weights/gate: 32 quads = 11 VGPR + 16 AGPR + 5 LDS (x4 gates: 44/64/20).
//  b2..b5: decoder gate-blocks. Thread owns rows {g*500+tid, g*500+250+tid}.
//    Per row 64 quads = 22 VGPR + 32 AGPR + 10 LDS (x2 rows: 44/64/20).
//    One cross-block round-trip/step: publish z, spin 3 flags, replicate c/h.
__launch_bounds__(256)
__global__ void k_lstm(const float* __restrict__ A_f, const float* __restrict__ A_b,
                       const float* __restrict__ A_d,
                       const float* __restrict__ Whh_f, const float* __restrict__ Whh_b,
                       const float* __restrict__ Whh_d,
                       float* __restrict__ hh, float* __restrict__ hdec,
                       float* zpub, int* flag_z) {
  const int b = blockIdx.x;
  const int tid = threadIdx.x;
  __shared__ __align__(16) uint4 wl[20 * 256];   // 81,920 B weight tails
  __shared__ __align__(16) uint4 h4[128];        // 2 x 64 quads (enc uses 2 x 32)
  const bool act = tid < 250;
  const int r0 = act ? tid : 249;                // clamped lane row

  if (tid < 128) h4[tid] = make_uint4(0, 0, 0, 0);

  if (b < 2) {
    // ================= encoder =================
    const float* A = (b == 0) ? A_f : A_b;
    const float* Whh = (b == 0) ? Whh_f : Whh_b;
    uint4 wv[4][11];
    uint32_t wa[256];
    for (int g = 0; g < 4; g++) {
      const float* wr = Whh + (size_t)(g * 250 + r0) * EHID;
#pragma unroll
      for (int qq = 0; qq < 5; qq++) {           // LDS quads 27..31 (guarded)
        int q = 27 + qq;
        float tmp[8];
#pragma unroll
        for (int cc = 0; cc < 8; cc++) { int col = 8 * q + cc; tmp[cc] = (col < EHID) ? wr[col] : 0.f; }
        wl[(g * 5 + qq) * 256 + tid] = packq(tmp);
      }
#pragma unroll
      for (int qq = 0; qq < 16; qq++) {          // AGPR quads 11..26
        uint4 pq = packq(wr + 8 * (11 + qq));
        int base = (g * 16 + qq) * 4;
        AW(wa[base + 0], pq.x); AW(wa[base + 1], pq.y);
        AW(wa[base + 2], pq.z); AW(wa[base + 3], pq.w);
      }
#pragma unroll
      for (int q = 0; q < 11; q++) wv[g][q] = packq(wr + 8 * q);   // VGPR quads 0..10
    }
    float c = 0.f;
    float a0 = A[r0], a1 = A[250 + r0], a2 = A[500 + r0], a3 = A[750 + r0];
    __syncthreads();
    for (int t = 0; t < HIST; t++) {
      const uint4* hb = h4 + (t & 1) * 32;
      float z0 = a0, z1 = a1, z2 = a2, z3 = a3;
      int tn = (t + 1 < HIST) ? t + 1 : t;
      a0 = A[tn * 1000 + r0];       a1 = A[tn * 1000 + 250 + r0];
      a2 = A[tn * 1000 + 500 + r0]; a3 = A[tn * 1000 + 750 + r0];
#pragma unroll
      for (int q = 0; q < 11; q++) {
        uint4 hq = hb[q];
        z0 = dotq(wv[0][q], hq, z0); z1 = dotq(wv[1][q], hq, z1);
        z2 = dotq(wv[2][q], hq, z2); z3 = dotq(wv[3][q], hq, z3);
      }
#pragma unroll
      for (int qq = 0; qq < 16; qq++) {
        uint4 hq = hb[11 + qq];
        uint4 u;
        ARQ(u, wa, (0 * 16 + qq) * 4); z0 = dotq(u, hq, z0);
        ARQ(u, wa, (1 * 16 + qq) * 4); z1 = dotq(u, hq, z1);
        ARQ(u, wa, (2 * 16 + qq) * 4); z2 = dotq(u, hq, z2);
        ARQ(u, wa, (3 * 16 + qq) * 4); z3 = dotq(u, hq, z3);
      }
#pragma unroll
      for (int qq = 0; qq < 5; qq++) {
        uint4 hq = hb[27 + qq];
        z0 = dotq(wl[(0 * 5 + qq) * 256 + tid], hq, z0);
        z1 = dotq(wl[(1 * 5 + qq) * 256 + tid], hq, z1);
        z2 = dotq(wl[(2 * 5 + qq) * 256 + tid], hq, z2);
        z3 = dotq(wl[(3 * 5 + qq) * 256 + tid], hq, z3);
      }
      float hval = 0.f;
      if (act) {
        c = sigf(z1) * c + sigf(z0) * tanh_f(z2);
        hval = sigf(z3) * tanh_f(c);
        if (b == 0) hh[(size_t)t * HID + tid] = hval;
        else        hh[(size_t)(HIST - 1 - t) * HID + 250 + tid] = hval;
      }
      float hother = __shfl_xor(hval, 1);
      uint32_t* hw = (uint32_t*)(h4 + ((t + 1) & 1) * 32);
      if (act && !(tid & 1)) hw[tid >> 1] = packh2(hval, hother);
      __syncthreads();
    }
  } else {
    // ================= decoder =================
    const int g = b - 2;
    const int u0 = r0, u1 = 250 + r0;
    uint4 wv[2][22];
    uint32_t wa[256];
    for (int r = 0; r < 2; r++) {
      const float* wr = Whh_d + (size_t)(g * 500 + (r ? u1 : u0)) * HID;
#pragma unroll
      for (int qq = 0; qq < 10; qq++) {          // LDS quads 54..63 (guarded)
        int q = 54 + qq;
        float tmp[8];
#pragma unroll
        for (int cc = 0; cc < 8; cc++) { int col = 8 * q + cc; tmp[cc] = (col < HID) ? wr[col] : 0.f; }
        wl[(r * 10 + qq) * 256 + tid] = packq(tmp);
      }
#pragma unroll
      for (int qq = 0; qq < 32; qq++) {          // AGPR quads 22..53
        uint4 pq = packq(wr + 8 * (22 + qq));
        int base = (r * 32 + qq) * 4;
        AW(wa[base + 0], pq.x); AW(wa[base + 1], pq.y);
        AW(wa[base + 2], pq.z); AW(wa[base + 3], pq.w);
      }
#pragma unroll
      for (int q = 0; q < 22; q++) wv[r][q] = packq(wr + 8 * q);   // VGPR 0..21
    }
    float cA = 0.f, cB = 0.f;
    float aA = A_d[g * 500 + u0], aB = A_d[g * 500 + u1];
    __syncthreads();
    for (int t = 0; t < TGT; t++) {
      const uint4* hb = h4 + (t & 1) * 64;
      float zA = aA, zB = aB;
      int tn = (t + 1 < TGT) ? t + 1 : t;
      aA = A_d[tn * 2000 + g * 500 + u0];
      aB = A_d[tn * 2000 + g * 500 + u1];
#pragma unroll
      for (int q = 0; q < 22; q++) {
        uint4 hq = hb[q];
        zA = dotq(wv[0][q], hq, zA); zB = dotq(wv[1][q], hq, zB);
      }
#pragma unroll
      for (int qq = 0; qq < 32; qq++) {
        uint4 hq = hb[22 + qq];
        uint4 u;
        ARQ(u, wa, (0 * 32 + qq) * 4); zA = dotq(u, hq, zA);
        ARQ(u, wa, (1 * 32 + qq) * 4); zB = dotq(u, hq, zB);
      }
#pragma unroll
      for (int qq = 0; qq < 10; qq++) {
        uint4 hq = hb[54 + qq];
        zA = dotq(wl[(0 * 10 + qq) * 256 + tid], hq, zA);
        zB = dotq(wl[(1 * 10 + qq) * 256 + tid], hq, zB);
      }
      // publish z for this gate (parity-double-buffered)
      float* zp = zpub + (t & 1) * 2048;
      if (act) { zp[g * 512 + u0] = zA; zp[g * 512 + u1] = zB; }
      __threadfence();
      __syncthreads();
      if (tid == 0) {
        __hip_atomic_store(&flag_z[t * 4 + g], 1, __ATOMIC_RELEASE, __HIP_MEMORY_SCOPE_AGENT);
        for (int gg = 0; gg < 4; gg++)
          if (gg != g) spin_flag(&flag_z[t * 4 + gg]);
      }
      __syncthreads();
      float hA = 0.f, hB = 0.f;
      if (act) {
        float zi0 = __hip_atomic_load(&zp[0 * 512 + u0], __ATOMIC_RELAXED, __HIP_MEMORY_SCOPE_AGENT);
        float zf0 = __hip_atomic_load(&zp[1 * 512 + u0], __ATOMIC_RELAXED, __HIP_MEMORY_SCOPE_AGENT);
        float zg0 = __hip_atomic_load(&zp[2 * 512 + u0], __ATOMIC_RELAXED, __HIP_MEMORY_SCOPE_AGENT);
        float zo0 = __hip_atomic_load(&zp[3 * 512 + u0], __ATOMIC_RELAXED, __HIP_MEMORY_SCOPE_AGENT);
        float zi1 = __hip_atomic_load(&zp[0 * 512 + u1], __ATOMIC_RELAXED, __HIP_MEMORY_SCOPE_AGENT);
        float zf1 = __hip_atomic_load(&zp[1 * 512 + u1], __ATOMIC_RELAXED, __HIP_MEMORY_SCOPE_AGENT);
        float zg1 = __hip_atomic_load(&zp[2 * 512 + u1], __ATOMIC_RELAXED, __HIP_MEMORY_SCOPE_AGENT);
        float zo1 = __hip_atomic_load(&zp[3 * 512 + u1], __ATOMIC_RELAXED, __HIP_MEMORY_SCOPE_AGENT);
        cA = sigf(zf0) * cA + sigf(zi0) * tanh_f(zg0);
        hA = sigf(zo0) * tanh_f(cA);
        cB = sigf(zf1) * cB + sigf(zi1) * tanh_f(zg1);
        hB = sigf(zo1) * tanh_f(cB);
        if (g == 3) {
          hdec[(size_t)t * HID + u0] = hA;
          hdec[(size_t)t * HID + u1] = hB;
        }
      }
      float hA1 = __shfl_xor(hA, 1), hB1 = __shfl_xor(hB, 1);
      uint32_t* hw = (uint32_t*)(h4 + ((t + 1) & 1) * 64);
      if (act && !(tid & 1)) {
        hw[tid >> 1] = packh2(hA, hA1);
        hw[125 + (tid >> 1)] = packh2(hB, hB1);
      }
      __syncthreads();
    }
  }
}

// ---------------- attention tables: S1 (256x1792), S2 (256x256) ----------------
__global__ void k_attn(const int* __restrict__ loc, const int* __restrict__ tim,
                       const int* __restrict__ cid,
                       const float* __restrict__ ts, const float* __restrict__ pd,
                       const float* __restrict__ pct,
                       float* __restrict__ S1, float* __restrict__ S2) {
  const int i = blockIdx.x;
  const int tid = threadIdx.x; // 256
  __shared__ float e[HIST];
  __shared__ float red[256];
  const int loc_i = loc[HIST + i], tim_i = tim[HIST + i];
  for (int tab = 0; tab < 3; tab++) {
    for (int jj = tid; jj < HIST; jj += 256) {
      float v;
      if (tab == 0)      v = 1.f / pd[(size_t)loc_i * 10000 + loc[jj]];
      else if (tab == 1) v = ts[tim_i * 48 + tim[jj]];
      else               v = pct[tim_i * 300 + cid[jj]];
      e[jj] = v;
    }
    __syncthreads();
    float mx = -1e30f;
    for (int jj = tid; jj < HIST; jj += 256) mx = fmaxf(mx, e[jj]);
    red[tid] = mx; __syncthreads();
    for (int s = 128; s > 0; s >>= 1) { if (tid < s) red[tid] = fmaxf(red[tid], red[tid + s]); __syncthreads(); }
    mx = red[0]; __syncthreads();
    float sm = 0.f;
    for (int jj = tid; jj < HIST; jj += 256) sm += __expf(e[jj] - mx);
    red[tid] = sm; __syncthreads();
    for (int s = 128; s > 0; s >>= 1) { if (tid < s) red[tid] += red[tid + s]; __syncthreads(); }
    float inv = 1.f / red[0]; __syncthreads();
    for (int jj = tid; jj < HIST; jj += 256) {
      float p = __expf(e[jj] - mx) * inv;
      if (tab == 0) S1[(size_t)i * HIST + jj] = p; else S1[(size_t)i * HIST + jj] += p;
    }
    __syncthreads();
  }
  const int lj = loc[HIST + tid], tj = tim[HIST + tid], cj = cid[HIST + tid];
  for (int tab = 0; tab < 3; tab++) {
    float v;
    if (tab == 0)      v = 1.f / pd[(size_t)loc_i * 10000 + lj];
    else if (tab == 1) v = ts[tim_i * 48 + tj];
    else               v = pct[tim_i * 300 + cj];
    if (tid > i) v = 0.f;
    red[tid] = v; __syncthreads();
    for (int s = 128; s > 0; s >>= 1) { if (tid < s) red[tid] = fmaxf(red[tid], red[tid + s]); __syncthreads(); }
    float mx = red[0]; __syncthreads();
    float ex = __expf(v - mx);
    red[tid] = ex; __syncthreads();
    for (int s = 128; s > 0; s >>= 1) { if (tid < s) red[tid] += red[tid + s]; __syncthreads(); }
    float p = ex / red[0]; __syncthreads();
    if (tab == 0) S2[(size_t)i * TGT + tid] = p; else S2[(size_t)i * TGT + tid] += p;
    __syncthreads();
  }
}

// ---------------- uid_emb ----------------
__global__ void k_uid(const int* __restrict__ uid, const float* __restrict__ emb_uid_w,
                      const float* __restrict__ fc_user_w, const float* __restrict__ fc_user_b,
                      float* __restrict__ uid_emb) {
  const int tid = threadIdx.x; // 512
  __shared__ float u[64];
  if (tid < 64) u[tid] = emb_uid_w[(size_t)uid[0] * 64 + tid];
  __syncthreads();
  if (tid < HID) {
    float a = fc_user_b[tid];
    for (int k = 0; k < 64; k++) a += u[k] * fc_user_w[tid * 64 + k];
    uid_emb[tid] = a;
  }
}

// ---------------- user attention + context_user ----------------
__global__ void k_user(const float* __restrict__ uid_emb, const float* __restrict__ hh,
                       float* __restrict__ out) {
  const int tid = threadIdx.x; // 1024
  __shared__ float s[HIST];
  __shared__ float red[1024];
  __shared__ float ue[HID];
  if (tid < HID) ue[tid] = uid_emb[tid];
  __syncthreads();
  for (int t = tid; t < HIST; t += 1024) {
    float a = 0.f;
    const float* hr = hh + (size_t)t * HID;
    for (int k = 0; k < HID; k++) a += ue[k] * hr[k];
    s[t] = a;
  }
  __syncthreads();
  float mx = -1e30f;
  for (int t = tid; t < HIST; t += 1024) mx = fmaxf(mx, s[t]);
  red[tid] = mx; __syncthreads();
  for (int st = 512; st > 0; st >>= 1) { if (tid < st) red[tid] = fmaxf(red[tid], red[tid + st]); __syncthreads(); }
  mx = red[0]; __syncthreads();
  float sm = 0.f;
  for (int t = tid; t < HIST; t += 1024) sm += __expf(s[t] - mx);
  red[tid] = sm; __syncthreads();
  for (int st = 512; st > 0; st >>= 1) { if (tid < st) red[tid] += red[tid + st]; __syncthreads(); }
  float inv = 1.f / red[0]; __syncthreads();
  for (int t = tid; t < HIST; t += 1024) s[t] = __expf(s[t] - mx) * inv;
  __syncthreads();
  if (tid < HID) {
    float a = 0.f;
    for (int t = 0; t < HIST; t++) a += s[t] * hh[(size_t)t * HID + tid];
    for (int i = 0; i < TGT; i++) out[(size_t)i * 1500 + 1000 + tid] = a;
  }
}

// ---------------- in-place log-softmax ----------------
__global__ void k_logsoftmax(float* __restrict__ y) {
  const int i = blockIdx.x;
  const int tid = threadIdx.x; // 1024
  float* r = y + (size_t)i * 10000;
  __shared__ float red[1024];
  float mx = -1e30f;
  for (int j = tid; j < 10000; j += 1024) mx = fmaxf(mx, r[j]);
  red[tid] = mx; __syncthreads();
  for (int s = 512; s > 0; s >>= 1) { if (tid < s) red[tid] = fmaxf(red[tid], red[tid + s]); __syncthreads(); }
  mx = red[0]; __syncthreads();
  float sm = 0.f;
  for (int j = tid; j < 10000; j += 1024) sm += __expf(r[j] - mx);
  red[tid] = sm; __syncthreads();
  for (int s = 512; s > 0; s >>= 1) { if (tid < s) red[tid] += red[tid + s]; __syncthreads(); }
  float lse = mx + __logf(red[0]);
  __syncthreads();
  for (int j = tid; j < 10000; j += 1024) r[j] = r[j] - lse;
}

extern "C" void kernel_launch(void* const* d_in, const int* in_sizes, int n_in,
                              void* d_out, int out_size, void* d_ws, size_t ws_size,
                              hipStream_t stream) {
  (void)in_sizes; (void)n_in; (void)out_size; (void)ws_size;
  const int* loc = (const int*)d_in[0];
  const int* tim = (const int*)d_in[1];
  const int* cid = (const int*)d_in[2];
  const int* uid = (const int*)d_in[3];
  const int* target = (const int*)d_in[4];
  const float* ts = (const float*)d_in[6];
  const float* pd = (const float*)d_in[7];
  const float* pct = (const float*)d_in[8];
  const float* weight = (const float*)d_in[9];
  const float* weight_cid = (const float*)d_in[10];
  const float* emb_uid_w = (const float*)d_in[11];
  const float* emb_tim_w = (const float*)d_in[12];
  const float* enc_Wih_f = (const float*)d_in[13];
  const float* enc_Whh_f = (const float*)d_in[14];
  const float* enc_b_f = (const float*)d_in[15];
  const float* enc_Wih_b = (const float*)d_in[16];
  const float* enc_Whh_b = (const float*)d_in[17];
  const float* enc_b_b = (const float*)d_in[18];
  const float* dec_Wih = (const float*)d_in[19];
  const float* dec_Whh = (const float*)d_in[20];
  const float* dec_b = (const float*)d_in[21];
  const float* fc_user_w = (const float*)d_in[22];
  const float* fc_user_b = (const float*)d_in[23];
  const float* fc_final_w = (const float*)d_in[24];
  const float* fc_final_b = (const float*)d_in[25];
  const float* fc_final2_w = (const float*)d_in[26];
  const float* fc_final2_b = (const float*)d_in[27];

  float* score = (float*)d_out;                  // 256*10000
  float* y1 = score + (size_t)TGT * 10000;       // 256*500
  float* te = y1 + (size_t)TGT * HID;            // 256*256

  float* ws = (float*)d_ws;
  float* x = ws;                                  // SEQ*INPUT
  float* A_f = x + (size_t)SEQ * INPUT;           // HIST*1000
  float* A_b = A_f + (size_t)HIST * 1000;         // HIST*1000
  float* A_d = A_b + (size_t)HIST * 1000;         // TGT*2000
  float* hh = A_d + (size_t)TGT * 2000;           // HIST*500
  float* hdec = hh + (size_t)HIST * HID;          // TGT*500
  float* S1 = hdec + (size_t)TGT * HID;           // TGT*HIST
  float* S2 = S1 + (size_t)TGT * HIST;            // TGT*TGT
  float* outb = S2 + (size_t)TGT * TGT;           // TGT*1500
  float* uid_emb = outb + (size_t)TGT * 1500;     // 512
  float* zpub = uid_emb + 512;                    // 2 * 4 * 512
  int* flag_z = (int*)(zpub + 2 * 2048);          // 4*TGT

  k_embed<<<dim3(SEQ + TGT), dim3(128), 0, stream>>>(loc, tim, cid, target, weight, emb_tim_w, weight_cid, x, te);

  k_gemm_t<<<dim3(16, 28), dim3(256), 0, stream>>>(x, INPUT, enc_Wih_f, enc_b_f, A_f, 1000, HIST, 1000, INPUT, 0);
  k_gemm_t<<<dim3(16, 28), dim3(256), 0, stream>>>(x, INPUT, enc_Wih_b, enc_b_b, A_b, 1000, HIST, 1000, INPUT, 1);
  k_gemm_t<<<dim3(32, 4), dim3(256), 0, stream>>>(x + (size_t)HIST * INPUT, INPUT, dec_Wih, dec_b, A_d, 2000, TGT, 2000, INPUT, 0);

  hipMemsetAsync(flag_z, 0, 4 * TGT * sizeof(int), stream);

  k_attn<<<dim3(TGT), dim3(256), 0, stream>>>(loc, tim, cid, ts, pd, pct, S1, S2);
  k_uid<<<dim3(1), dim3(512), 0, stream>>>(uid, emb_uid_w, fc_user_w, fc_user_b, uid_emb);

  k_lstm<<<dim3(6), dim3(256), 0, stream>>>(A_f, A_b, A_d, enc_Whh_f, enc_Whh_b, dec_Whh,
                                            hh, hdec, zpub, flag_z);

  k_user<<<dim3(1), dim3(1024), 0, stream>>>(uid_emb, hh, outb);
  k_gemm_nn<<<dim3(8, 4), dim3(256), 0, stream>>>(S2, TGT, hdec, HID, uid_emb, outb, 1500, TGT, HID, TGT);
  k_gemm_nn<<<dim3(8, 4), dim3(256), 0, stream>>>(S1, HIST, hh, HID, nullptr, outb + 500, 1500, TGT, HID, HIST);

  k_gemm_t<<<dim3(157, 4), dim3(256), 0, stream>>>(outb, 1500, fc_final_w, fc_final_b, score, 10000, TGT, 10000, 1500, 0);
  k_gemm_t<<<dim3(8, 4), dim3(256), 0, stream>>>(outb, 1500, fc_final2_w, fc_final2_b, y1, 500, TGT, 500, 1500, 0);

  k_logsoftmax<<<dim3(TGT), dim3(1024), 0, stream>>>(score);
}

// Round 8
// 5369.450 us; speedup vs baseline: 9.3461x; 9.3461x over previous
//
#include <hip/hip_runtime.h>
#include <stdint.h>

#define HIST 1792
#define TGT 256
#define SEQ 2048
#define INPUT 352
#define EHID 250
#define HID 500

typedef _Float16 h2_t __attribute__((ext_vector_type(2)));

static __device__ __forceinline__ float fdot2(uint32_t a, uint32_t b, float c) {
  return __builtin_amdgcn_fdot2(__builtin_bit_cast(h2_t, a),
                                __builtin_bit_cast(h2_t, b), c, false);
}
static __device__ __forceinline__ uint32_t packh2(float lo, float hi) {
  h2_t h; h[0] = (_Float16)lo; h[1] = (_Float16)hi;
  return __builtin_bit_cast(uint32_t, h);
}
static __device__ __forceinline__ uint4 packq(const float* p) {
  uint4 r;
  r.x = packh2(p[0], p[1]); r.y = packh2(p[2], p[3]);
  r.z = packh2(p[4], p[5]); r.w = packh2(p[6], p[7]);
  return r;
}
static __device__ __forceinline__ float dotq(uint4 w, uint4 h, float acc) {
  acc = fdot2(w.x, h.x, acc); acc = fdot2(w.y, h.y, acc);
  acc = fdot2(w.z, h.z, acc); acc = fdot2(w.w, h.w, acc);
  return acc;
}
static __device__ __forceinline__ float sigf(float x) {
  x = fminf(fmaxf(x, -30.f), 30.f);
  return 1.f / (1.f + __expf(-x));
}
static __device__ __forceinline__ float tanh_f(float x) {
  x = fminf(fmaxf(x, -15.f), 15.f);
  float e = __expf(2.f * x);
  return (e - 1.f) / (e + 1.f);
}
static __device__ __forceinline__ void spin_flag(volatile int* f) {
  while (__hip_atomic_load(f, __ATOMIC_ACQUIRE, __HIP_MEMORY_SCOPE_AGENT) == 0)
    __builtin_amdgcn_s_sleep(2);
}
// AGPR store/load: NON-volatile (dataflow-ordered, scheduler may interleave).
#define AW(dst, src) asm("v_accvgpr_write_b32 %0, %1" : "=a"(dst) : "v"(src))
#define AR(dst, src) asm("v_accvgpr_read_b32 %0, %1" : "=v"(dst) : "a"(src))
#define ARQ(dst, arr, base) do { AR(dst.x, arr[(base)+0]); AR(dst.y, arr[(base)+1]); AR(dst.z, arr[(base)+2]); AR(dst.w, arr[(base)+3]); } while(0)

// ---------------- embedding gather + target_emb ----------------
__global__ void k_embed(const int* __restrict__ loc, const int* __restrict__ tim,
                        const int* __restrict__ cid, const int* __restrict__ target,
                        const float* __restrict__ weight, const float* __restrict__ emb_tim_w,
                        const float* __restrict__ weight_cid,
                        float* __restrict__ x, float* __restrict__ te) {
  int t = blockIdx.x, tid = threadIdx.x;
  if (t < SEQ) {
    int l = loc[t], tm = tim[t], cd = cid[t];
    float* xr = x + (size_t)t * INPUT;
    for (int k = tid; k < 256; k += blockDim.x) xr[k] = weight[(size_t)l * 256 + k];
    for (int k = tid; k < 32; k += blockDim.x)  xr[256 + k] = emb_tim_w[tm * 32 + k];
    for (int k = tid; k < 64; k += blockDim.x)  xr[288 + k] = weight_cid[cd * 64 + k];
  } else {
    int i = t - SEQ;
    int tg = target[i];
    for (int k = tid; k < 256; k += blockDim.x) te[(size_t)i * 256 + k] = weight[(size_t)tg * 256 + k];
  }
}

// ---------------- C[M][N] = op(A)[M][K] @ W[N][K]^T + bias ----------------
__global__ void k_gemm_t(const float* __restrict__ A, int lda,
                         const float* __restrict__ W, const float* __restrict__ bias,
                         float* __restrict__ C, int ldc,
                         int M, int N, int K, int revA) {
  __shared__ float As[16][65];
  __shared__ float Ws[16][65];
  const int bn = blockIdx.x * 64, bm = blockIdx.y * 64;
  const int tid = threadIdx.x;
  const int tx = tid & 15, ty = tid >> 4;
  float acc[4][4] = {};
  for (int k0 = 0; k0 < K; k0 += 16) {
    for (int i = tid; i < 1024; i += 256) {
      int m = i >> 4, k = i & 15;
      int gm = bm + m, gk = k0 + k;
      float v = 0.f;
      if (gm < M && gk < K) { int am = revA ? (M - 1 - gm) : gm; v = A[(size_t)am * lda + gk]; }
      As[k][m] = v;
    }
    for (int i = tid; i < 1024; i += 256) {
      int n = i >> 4, k = i & 15;
      int gn = bn + n, gk = k0 + k;
      float v = 0.f;
      if (gn < N && gk < K) v = W[(size_t)gn * K + gk];
      Ws[k][n] = v;
    }
    __syncthreads();
#pragma unroll
    for (int k = 0; k < 16; k++) {
      float a0 = As[k][ty * 4 + 0], a1 = As[k][ty * 4 + 1], a2 = As[k][ty * 4 + 2], a3 = As[k][ty * 4 + 3];
      float b0 = Ws[k][tx * 4 + 0], b1 = Ws[k][tx * 4 + 1], b2 = Ws[k][tx * 4 + 2], b3 = Ws[k][tx * 4 + 3];
      acc[0][0] += a0 * b0; acc[0][1] += a0 * b1; acc[0][2] += a0 * b2; acc[0][3] += a0 * b3;
      acc[1][0] += a1 * b0; acc[1][1] += a1 * b1; acc[1][2] += a1 * b2; acc[1][3] += a1 * b3;
      acc[2][0] += a2 * b0; acc[2][1] += a2 * b1; acc[2][2] += a2 * b2; acc[2][3] += a2 * b3;
      acc[3][0] += a3 * b0; acc[3][1] += a3 * b1; acc[3][2] += a3 * b2; acc[3][3] += a3 * b3;
    }
    __syncthreads();
  }
  for (int i = 0; i < 4; i++) {
    int gm = bm + ty * 4 + i; if (gm >= M) continue;
    for (int j = 0; j < 4; j++) {
      int gn = bn + tx * 4 + j; if (gn >= N) continue;
      C[(size_t)gm * ldc + gn] = acc[i][j] + (bias ? bias[gn] : 0.f);
    }
  }
}

// ---------------- C[M][N] = A[M][K] @ B[K][N] + addvec[N] ----------------
__global__ void k_gemm_nn(const float* __restrict__ A, int lda,
                          const float* __restrict__ B, int ldb,
                          const float* __restrict__ addvec,
                          float* __restrict__ C, int ldc,
                          int M, int N, int K) {
  __shared__ float As[16][65];
  __shared__ float Bs[16][65];
  const int bn = blockIdx.x * 64, bm = blockIdx.y * 64;
  const int tid = threadIdx.x;
  const int tx = tid & 15, ty = tid >> 4;
  float acc[4][4] = {};
  for (int k0 = 0; k0 < K; k0 += 16) {
    for (int i = tid; i < 1024; i += 256) {
      int m = i >> 4, k = i & 15;
      int gm = bm + m, gk = k0 + k;
      float v = 0.f;
      if (gm < M && gk < K) v = A[(size_t)gm * lda + gk];
      As[k][m] = v;
    }
    for (int i = tid; i < 1024; i += 256) {
      int k = i >> 6, n = i & 63;
      int gk = k0 + k, gn = bn + n;
      float v = 0.f;
      if (gk < K && gn < N) v = B[(size_t)gk * ldb + gn];
      Bs[k][n] = v;
    }
    __syncthreads();
#pragma unroll
    for (int k = 0; k < 16; k++) {
      float a0 = As[k][ty * 4 + 0], a1 = As[k][ty * 4 + 1], a2 = As[k][ty * 4 + 2], a3 = As[k][ty * 4 + 3];
      float b0 = Bs[k][tx * 4 + 0], b1 = Bs[k][tx * 4 + 1], b2 = Bs[k][tx * 4 + 2], b3 = Bs[k][tx * 4 + 3];
      acc[0][0] += a0 * b0; acc[0][1] += a0 * b1; acc[0][2] += a0 * b2; acc[0][3] += a0 * b3;
      acc[1][0] += a1 * b0; acc[1][1] += a1 * b1; acc[1][2] += a1 * b2; acc[1][3] += a1 * b3;
      acc[2][0] += a2 * b0; acc[2][1] += a2 * b1; acc[2][2] += a2 * b2; acc[2][3] += a2 * b3;
      acc[3][0] += a3 * b0; acc[3][1] += a3 * b1; acc[3][2] += a3 * b2; acc[3][3] += a3 * b3;
    }
    __syncthreads();
  }
  for (int i = 0; i < 4; i++) {
    int gm = bm + ty * 4 + i; if (gm >= M) continue;
    for (int j = 0; j < 4; j++) {
      int gn = bn + tx * 4 + j; if (gn >= N) continue;
      C[(size_t)gm * ldc + gn] = acc[i][j] + (addvec ? addvec[gn] : 0.f);
    }
  }
}

// ---------------- LSTMs ----------------
// 6 blocks x 512 threads. b0/b1 = encoders (single block, 2 rows/thread);
// b2..b5 = decoder gates i,f,g,o (1 row/thread, R2 flag handshake).
// Per-thread 250 weight-dwords tiered 20q VGPR + 32q AGPR + 12q LDS:
// zero scratch; A(t+1) prefetched; h double-buffered; non-volatile AGPR asm.
#define WQL 12
#define WBYTES (WQL * 512 * 16)   // 98,304 B
__launch_bounds__(512)
__global__ void k_lstm(const float* __restrict__ A_f, const float* __restrict__ A_b,
                       const float* __restrict__ A_d,
                       const float* __restrict__ Whh_f, const float* __restrict__ Whh_b,
                       const float* __restrict__ Whh_d,
                       float* __restrict__ hh, float* __restrict__ hdec,
                       float* zpub, uint32_t* hpub, int* flag_z, int* flag_h) {
  const int b = blockIdx.x;
  const int tid = threadIdx.x;
  __shared__ __align__(16) unsigned char smem[WBYTES + 2048 + 4096];
  uint4* wl = (uint4*)smem;
  uint4* hbuf = (uint4*)(smem + WBYTES);          // 2 x 64 quads (enc uses 2 x 32)
  float* zbuf = (float*)(smem + WBYTES + 2048);   // 1000 floats

  if (tid < 128) hbuf[tid] = make_uint4(0, 0, 0, 0);

  if (b < 2) {
    // ================= encoder =================
    const float* A = (b == 0) ? A_f : A_b;
    const float* Whh = (b == 0) ? Whh_f : Whh_b;
    const bool act = tid < 500;
    uint4 wv0[10], wv1[10];      // quads 0..9   (cols 0..79)
    uint32_t wa[128];            // quads 10..25 (cols 80..207), rows 0/1
    if (act) {
      const float* wr0 = Whh + (size_t)tid * EHID;
      const float* wr1 = Whh + (size_t)(tid + 500) * EHID;
      // LDS quads 26..31 (cols 208..255, pad >= 250)
#pragma unroll
      for (int q = 0; q < 6; q++) {
        float t0[8], t1[8];
#pragma unroll
        for (int cc = 0; cc < 8; cc++) {
          int col = 208 + 8 * q + cc;
          t0[cc] = (col < EHID) ? wr0[col] : 0.f;
          t1[cc] = (col < EHID) ? wr1[col] : 0.f;
        }
        wl[(q * 2 + 0) * 512 + tid] = packq(t0);
        wl[(q * 2 + 1) * 512 + tid] = packq(t1);
      }
      // AGPR quads 10..25
#pragma unroll
      for (int k = 0; k < 16; k++) {
        uint4 p0 = packq(wr0 + 8 * (10 + k));
        uint4 p1 = packq(wr1 + 8 * (10 + k));
        AW(wa[k * 4 + 0], p0.x); AW(wa[k * 4 + 1], p0.y);
        AW(wa[k * 4 + 2], p0.z); AW(wa[k * 4 + 3], p0.w);
        AW(wa[64 + k * 4 + 0], p1.x); AW(wa[64 + k * 4 + 1], p1.y);
        AW(wa[64 + k * 4 + 2], p1.z); AW(wa[64 + k * 4 + 3], p1.w);
      }
#pragma unroll
      for (int q = 0; q < 10; q++) { wv0[q] = packq(wr0 + 8 * q); wv1[q] = packq(wr1 + 8 * q); }
    }
    float c = 0.f;
    float aA = act ? A[tid] : 0.f;
    float aB = act ? A[500 + tid] : 0.f;
    __syncthreads();
    for (int t = 0; t < HIST; t++) {
      const uint4* hb = hbuf + (t & 1) * 32;
      if (act) {
        float z0 = aA, z1 = aB, y0 = 0.f, y1 = 0.f;
        int tn = (t + 1 < HIST) ? t + 1 : t;
        aA = A[tn * 1000 + tid];
        aB = A[tn * 1000 + 500 + tid];
#pragma unroll
        for (int q = 0; q < 10; q++) {
          uint4 hq = hb[q];
          z0 = dotq(wv0[q], hq, z0);
          z1 = dotq(wv1[q], hq, z1);
        }
#pragma unroll
        for (int k = 0; k < 16; k++) {
          uint4 hq = hb[10 + k];
          uint4 u0, u1;
          ARQ(u0, wa, k * 4);
          ARQ(u1, wa, 64 + k * 4);
          y0 = dotq(u0, hq, y0);
          y1 = dotq(u1, hq, y1);
        }
#pragma unroll
        for (int q = 0; q < 6; q++) {
          uint4 hq = hb[26 + q];
          z0 = dotq(wl[(q * 2 + 0) * 512 + tid], hq, z0);
          z1 = dotq(wl[(q * 2 + 1) * 512 + tid], hq, z1);
        }
        zbuf[tid] = z0 + y0;
        zbuf[500 + tid] = z1 + y1;
      }
      __syncthreads();
      float hval = 0.f;
      if (tid < EHID) {
        float zi = zbuf[tid], zf = zbuf[250 + tid], zg = zbuf[500 + tid], zo = zbuf[750 + tid];
        c = sigf(zf) * c + sigf(zi) * tanh_f(zg);
        hval = sigf(zo) * tanh_f(c);
        if (b == 0) hh[(size_t)t * HID + tid] = hval;
        else        hh[(size_t)(HIST - 1 - t) * HID + EHID + tid] = hval;
      }
      float hother = __shfl_xor(hval, 1);
      uint32_t* hw = (uint32_t*)(hbuf + ((t + 1) & 1) * 32);
      if (tid < EHID && !(tid & 1)) hw[tid >> 1] = packh2(hval, hother);
      __syncthreads();
    }
  } else {
    // ================= decoder =================
    const int gi = b - 2;            // 0=i, 1=f, 2=g, 3=o
    const int j = tid;
    const bool act = (j < 500);
    uint4 wv[20];                    // quads 0..19  (cols 0..159)
    uint32_t wa[128];                // quads 20..51 (cols 160..415)
    if (act) {
      const float* wr = Whh_d + (size_t)(gi * 500 + j) * HID;
      // LDS quads 52..63 (cols 416..511, pad >= 500)
#pragma unroll
      for (int q = 0; q < 12; q++) {
        float tmp[8];
#pragma unroll
        for (int cc = 0; cc < 8; cc++) {
          int col = 416 + 8 * q + cc;
          tmp[cc] = (col < HID) ? wr[col] : 0.f;
        }
        wl[q * 512 + tid] = packq(tmp);
      }
#pragma unroll
      for (int k = 0; k < 32; k++) {
        uint4 pq = packq(wr + 8 * (20 + k));
        AW(wa[k * 4 + 0], pq.x); AW(wa[k * 4 + 1], pq.y);
        AW(wa[k * 4 + 2], pq.z); AW(wa[k * 4 + 3], pq.w);
      }
#pragma unroll
      for (int q = 0; q < 20; q++) wv[q] = packq(wr + 8 * q);
    }
    uint32_t* hdd = (uint32_t*)hbuf;
    float c = 0.f;
    float aD = act ? A_d[gi * 500 + j] : 0.f;
    __syncthreads();
    for (int t = 0; t < TGT; t++) {
      const uint4* hb = hbuf + (t & 1) * 64;
      float z = 0.f;
      if (act) {
        float z0 = aD, z1 = 0.f, z2 = 0.f, z3 = 0.f;
        int tn = (t + 1 < TGT) ? t + 1 : t;
        aD = A_d[tn * 2000 + gi * 500 + j];
#pragma unroll
        for (int q = 0; q < 20; q += 2) {
          z0 = dotq(wv[q], hb[q], z0);
          z1 = dotq(wv[q + 1], hb[q + 1], z1);
        }
#pragma unroll
        for (int k = 0; k < 32; k += 2) {
          uint4 u0, u1;
          ARQ(u0, wa, k * 4);
          ARQ(u1, wa, (k + 1) * 4);
          z2 = dotq(u0, hb[20 + k], z2);
          z3 = dotq(u1, hb[21 + k], z3);
        }
#pragma unroll
        for (int q = 0; q < 12; q += 2) {
          z0 = dotq(wl[q * 512 + tid], hb[52 + q], z0);
          z1 = dotq(wl[(q + 1) * 512 + tid], hb[53 + q], z1);
        }
        z = (z0 + z1) + (z2 + z3);
      }
      if (gi < 3) {
        if (act) zpub[gi * 512 + j] = z;
        __threadfence();
        __syncthreads();
        if (tid == 0) {
          __hip_atomic_store(&flag_z[t * 3 + gi], 1, __ATOMIC_RELEASE, __HIP_MEMORY_SCOPE_AGENT);
          spin_flag(&flag_h[t]);
        }
        __syncthreads();
        uint32_t* hw = (uint32_t*)(hbuf + ((t + 1) & 1) * 64);
        if (tid < 250)
          hw[tid] = __hip_atomic_load(&hpub[tid], __ATOMIC_RELAXED, __HIP_MEMORY_SCOPE_AGENT);
        __syncthreads();
      } else {
        if (tid == 0) {
          spin_flag(&flag_z[t * 3 + 0]);
          spin_flag(&flag_z[t * 3 + 1]);
          spin_flag(&flag_z[t * 3 + 2]);
        }
        __syncthreads();
        float hval = 0.f;
        if (act) {
          float zi = __hip_atomic_load(&zpub[0 * 512 + j], __ATOMIC_RELAXED, __HIP_MEMORY_SCOPE_AGENT);
          float zf = __hip_atomic_load(&zpub[1 * 512 + j], __ATOMIC_RELAXED, __HIP_MEMORY_SCOPE_AGENT);
          float zg = __hip_atomic_load(&zpub[2 * 512 + j], __ATOMIC_RELAXED, __HIP_MEMORY_SCOPE_AGENT);
          c = sigf(zf) * c + sigf(zi) * tanh_f(zg);
          hval = sigf(z) * tanh_f(c);
          hdec[(size_t)t * HID + j] = hval;
        }
        float hother = __shfl_xor(hval, 1);
        uint32_t* hw = (uint32_t*)(hbuf + ((t + 1) & 1) * 64);
        if (act && !(j & 1)) {
          uint32_t p = packh2(hval, hother);
          hw[j >> 1] = p;
          __hip_atomic_store(&hpub[j >> 1], p, __ATOMIC_RELAXED, __HIP_MEMORY_SCOPE_AGENT);
        }
        __threadfence();
        __syncthreads();
        if (tid == 0)
          __hip_atomic_store(&flag_h[t], 1, __ATOMIC_RELEASE, __HIP_MEMORY_SCOPE_AGENT);
      }
    }
  }
}

// ---------------- attention tables: S1 (256x1792), S2 (256x256) ----------------
__global__ void k_attn(const int* __restrict__ loc, const int* __restrict__ tim,
                       const int* __restrict__ cid,
                       const float* __restrict__ ts, const float* __restrict__ pd,
                       const float* __restrict__ pct,
                       float* __restrict__ S1, float* __restrict__ S2) {
  const int i = blockIdx.x;
  const int tid = threadIdx.x; // 256
  __shared__ float e[HIST];
  __shared__ float red[256];
  const int loc_i = loc[HIST + i], tim_i = tim[HIST + i];
  for (int tab = 0; tab < 3; tab++) {
    for (int jj = tid; jj < HIST; jj += 256) {
      float v;
      if (tab == 0)      v = 1.f / pd[(size_t)loc_i * 10000 + loc[jj]];
      else if (tab == 1) v = ts[tim_i * 48 + tim[jj]];
      else               v = pct[tim_i * 300 + cid[jj]];
      e[jj] = v;
    }
    __syncthreads();
    float mx = -1e30f;
    for (int jj = tid; jj < HIST; jj += 256) mx = fmaxf(mx, e[jj]);
    red[tid] = mx; __syncthreads();
    for (int s = 128; s > 0; s >>= 1) { if (tid < s) red[tid] = fmaxf(red[tid], red[tid + s]); __syncthreads(); }
    mx = red[0]; __syncthreads();
    float sm = 0.f;
    for (int jj = tid; jj < HIST; jj += 256) sm += __expf(e[jj] - mx);
    red[tid] = sm; __syncthreads();
    for (int s = 128; s > 0; s >>= 1) { if (tid < s) red[tid] += red[tid + s]; __syncthreads(); }
    float inv = 1.f / red[0]; __syncthreads();
    for (int jj = tid; jj < HIST; jj += 256) {
      float p = __expf(e[jj] - mx) * inv;
      if (tab == 0) S1[(size_t)i * HIST + jj] = p; else S1[(size_t)i * HIST + jj] += p;
    }
    __syncthreads();
  }
  const int lj = loc[HIST + tid], tj = tim[HIST + tid], cj = cid[HIST + tid];
  for (int tab = 0; tab < 3; tab++) {
    float v;
    if (tab == 0)      v = 1.f / pd[(size_t)loc_i * 10000 + lj];
    else if (tab == 1) v = ts[tim_i * 48 + tj];
    else               v = pct[tim_i * 300 + cj];
    if (tid > i) v = 0.f;
    red[tid] = v; __syncthreads();
    for (int s = 128; s > 0; s >>= 1) { if (tid < s) red[tid] = fmaxf(red[tid], red[tid + s]); __syncthreads(); }
    float mx = red[0]; __syncthreads();
    float ex = __expf(v - mx);
    red[tid] = ex; __syncthreads();
    for (int s = 128; s > 0; s >>= 1) { if (tid < s) red[tid] += red[tid + s]; __syncthreads(); }
    float p = ex / red[0]; __syncthreads();
    if (tab == 0) S2[(size_t)i * TGT + tid] = p; else S2[(size_t)i * TGT + tid] += p;
    __syncthreads();
  }
}

// ---------------- uid_emb ----------------
__global__ void k_uid(const int* __restrict__ uid, const float* __restrict__ emb_uid_w,
                      const float* __restrict__ fc_user_w, const float* __restrict__ fc_user_b,
                      float* __restrict__ uid_emb) {
  const int tid = threadIdx.x; // 512
  __shared__ float u[64];
  if (tid < 64) u[tid] = emb_uid_w[(size_t)uid[0] * 64 + tid];
  __syncthreads();
  if (tid < HID) {
    float a = fc_user_b[tid];
    for (int k = 0; k < 64; k++) a += u[k] * fc_user_w[tid * 64 + k];
    uid_emb[tid] = a;
  }
}

// ---------------- user attention + context_user ----------------
__global__ void k_user(const float* __restrict__ uid_emb, const float* __restrict__ hh,
                       float* __restrict__ out) {
  const int tid = threadIdx.x; // 1024
  __shared__ float s[HIST];
  __shared__ float red[1024];
  __shared__ float ue[HID];
  if (tid < HID) ue[tid] = uid_emb[tid];
  __syncthreads();
  for (int t = tid; t < HIST; t += 1024) {
    float a = 0.f;
    const float* hr = hh + (size_t)t * HID;
    for (int k = 0; k < HID; k++) a += ue[k] * hr[k];
    s[t] = a;
  }
  __syncthreads();
  float mx = -1e30f;
  for (int t = tid; t < HIST; t += 1024) mx = fmaxf(mx, s[t]);
  red[tid] = mx; __syncthreads();
  for (int st = 512; st > 0; st >>= 1) { if (tid < st) red[tid] = fmaxf(red[tid], red[tid + st]); __syncthreads(); }
  mx = red[0]; __syncthreads();
  float sm = 0.f;
  for (int t = tid; t < HIST; t += 1024) sm += __expf(s[t] - mx);
  red[tid] = sm; __syncthreads();
  for (int st = 512; st > 0; st >>= 1) { if (tid < st) red[tid] += red[tid + st]; __syncthreads(); }
  float inv = 1.f / red[0]; __syncthreads();
  for (int t = tid; t < HIST; t += 1024) s[t] = __expf(s[t] - mx) * inv;
  __syncthreads();
  if (tid < HID) {
    float a = 0.f;
    for (int t = 0; t < HIST; t++) a += s[t] * hh[(size_t)t * HID + tid];
    for (int i = 0; i < TGT; i++) out[(size_t)i * 1500 + 1000 + tid] = a;
  }
}

// ---------------- in-place log-softmax ----------------
__global__ void k_logsoftmax(float* __restrict__ y) {
  const int i = blockIdx.x;
  const int tid = threadIdx.x; // 1024
  float* r = y + (size_t)i * 10000;
  __shared__ float red[1024];
  float mx = -1e30f;
  for (int j = tid; j < 10000; j += 1024) mx = fmaxf(mx, r[j]);
  red[tid] = mx; __syncthreads();
  for (int s = 512; s > 0; s >>= 1) { if (tid < s) red[tid] = fmaxf(red[tid], red[tid + s]); __syncthreads(); }
  mx = red[0]; __syncthreads();
  float sm = 0.f;
  for (int j = tid; j < 10000; j += 1024) sm += __expf(r[j] - mx);
  red[tid] = sm; __syncthreads();
  for (int s = 512; s > 0; s >>= 1) { if (tid < s) red[tid] += red[tid + s]; __syncthreads(); }
  float lse = mx + __logf(red[0]);
  __syncthreads();
  for (int j = tid; j < 10000; j += 1024) r[j] = r[j] - lse;
}

extern "C" void kernel_launch(void* const* d_in, const int* in_sizes, int n_in,
                              void* d_out, int out_size, void* d_ws, size_t ws_size,
                              hipStream_t stream) {
  (void)in_sizes; (void)n_in; (void)out_size; (void)ws_size;
  const int* loc = (const int*)d_in[0];
  const int* tim = (const int*)d_in[1];
  const int* cid = (const int*)d_in[2];
  const int* uid = (const int*)d_in[3];
  const int* target = (const int*)d_in[4];
  const float* ts = (const float*)d_in[6];
  const float* pd = (const float*)d_in[7];
  const float* pct = (const float*)d_in[8];
  const float* weight = (const float*)d_in[9];
  const float* weight_cid = (const float*)d_in[10];
  const float* emb_uid_w = (const float*)d_in[11];
  const float* emb_tim_w = (const float*)d_in[12];
  const float* enc_Wih_f = (const float*)d_in[13];
  const float* enc_Whh_f = (const float*)d_in[14];
  const float* enc_b_f = (const float*)d_in[15];
  const float* enc_Wih_b = (const float*)d_in[16];
  const float* enc_Whh_b = (const float*)d_in[17];
  const float* enc_b_b = (const float*)d_in[18];
  const float* dec_Wih = (const float*)d_in[19];
  const float* dec_Whh = (const float*)d_in[20];
  const float* dec_b = (const float*)d_in[21];
  const float* fc_user_w = (const float*)d_in[22];
  const float* fc_user_b = (const float*)d_in[23];
  const float* fc_final_w = (const float*)d_in[24];
  const float* fc_final_b = (const float*)d_in[25];
  const float* fc_final2_w = (const float*)d_in[26];
  const float* fc_final2_b = (const float*)d_in[27];

  float* score = (float*)d_out;                  // 256*10000
  float* y1 = score + (size_t)TGT * 10000;       // 256*500
  float* te = y1 + (size_t)TGT * HID;            // 256*256

  float* ws = (float*)d_ws;
  float* x = ws;                                  // SEQ*INPUT
  float* A_f = x + (size_t)SEQ * INPUT;           // HIST*1000
  float* A_b = A_f + (size_t)HIST * 1000;         // HIST*1000
  float* A_d = A_b + (size_t)HIST * 1000;         // TGT*2000
  float* hh = A_d + (size_t)TGT * 2000;           // HIST*500
  float* hdec = hh + (size_t)HIST * HID;          // TGT*500
  float* S1 = hdec + (size_t)TGT * HID;           // TGT*HIST
  float* S2 = S1 + (size_t)TGT * HIST;            // TGT*TGT
  float* outb = S2 + (size_t)TGT * TGT;           // TGT*1500
  float* uid_emb = outb + (size_t)TGT * 1500;     // 512
  float* zpub = uid_emb + 512;                    // 3*512
  uint32_t* hpub = (uint32_t*)(zpub + 3 * 512);   // 256
  int* flag_z = (int*)(hpub + 256);               // 3*256
  int* flag_h = flag_z + 3 * TGT;                 // 256

  k_embed<<<dim3(SEQ + TGT), dim3(128), 0, stream>>>(loc, tim, cid, target, weight, emb_tim_w, weight_cid, x, te);

  k_gemm_t<<<dim3(16, 28), dim3(256), 0, stream>>>(x, INPUT, enc_Wih_f, enc_b_f, A_f, 1000, HIST, 1000, INPUT, 0);
  k_gemm_t<<<dim3(16, 28), dim3(256), 0, stream>>>(x, INPUT, enc_Wih_b, enc_b_b, A_b, 1000, HIST, 1000, INPUT, 1);
  k_gemm_t<<<dim3(32, 4), dim3(256), 0, stream>>>(x + (size_t)HIST * INPUT, INPUT, dec_Wih, dec_b, A_d, 2000, TGT, 2000, INPUT, 0);

  hipMemsetAsync(flag_z, 0, 4 * TGT * sizeof(int), stream);

  k_attn<<<dim3(TGT), dim3(256), 0, stream>>>(loc, tim, cid, ts, pd, pct, S1, S2);
  k_uid<<<dim3(1), dim3(512), 0, stream>>>(uid, emb_uid_w, fc_user_w, fc_user_b, uid_emb);

  k_lstm<<<dim3(6), dim3(512), 0, stream>>>(A_f, A_b, A_d, enc_Whh_f, enc_Whh_b, dec_Whh,
                                            hh, hdec, zpub, hpub, flag_z, flag_h);

  k_user<<<dim3(1), dim3(1024), 0, stream>>>(uid_emb, hh, outb);
  k_gemm_nn<<<dim3(8, 4), dim3(256), 0, stream>>>(S2, TGT, hdec, HID, uid_emb, outb, 1500, TGT, HID, TGT);
  k_gemm_nn<<<dim3(8, 4), dim3(256), 0, stream>>>(S1, HIST, hh, HID, nullptr, outb + 500, 1500, TGT, HID, HIST);

  k_gemm_t<<<dim3(157, 4), dim3(256), 0, stream>>>(outb, 1500, fc_final_w, fc_final_b, score, 10000, TGT, 10000, 1500, 0);
  k_gemm_t<<<dim3(8, 4), dim3(256), 0, stream>>>(outb, 1500, fc_final2_w, fc_final2_b, y1, 500, TGT, 500, 1500, 0);

  k_logsoftmax<<<dim3(TGT), dim3(1024), 0, stream>>>(score);
}